// Round 1
// baseline (703.383 us; speedup 1.0000x reference)
//
#include <hip/hip_runtime.h>

// ---------------------------------------------------------------------------
// Only the drug pathway matters: pos/neg depend only on h_d, which depends
// only on feat_drug + dd edges. Gene-side computation is dead code.
// Pipeline:
//   deg[n]   = sum over dd edges of [dst==n]                (once)
//   msg1     = feat_drug @ W1_dd          [20000 x 64]
//   self1    = feat_drug @ W1_self_drug   [20000 x 64]
//   agg1     = scatter_sum(msg1[src] -> dst) / max(deg,1)
//   h1       = relu(agg1 + self1 + b1)                      (in place in agg1)
//   msg2     = h1 @ W2_dd                 [20000 x 32]
//   self2    = h1 @ W2_self_drug
//   agg2     = scatter-mean, h2 = agg2 + self2 + b2         (in place in agg2)
//   pos[e]   = sum_k h2[dd_src[e]][k] * w_rel[k] * h2[dd_dst[e]][k]
//   neg[e]   = same with neg_src/neg_dst
// ---------------------------------------------------------------------------

// out[m][n] = sum_k A[m][k] * W[k][n];  blockDim = (KOUT, 256/KOUT)
template<int KIN, int KOUT>
__global__ __launch_bounds__(256) void gemm_kernel(const float* __restrict__ A,
                                                   const float* __restrict__ W,
                                                   float* __restrict__ out, int M) {
    __shared__ float Ws[KIN * KOUT];
    const int tid = threadIdx.y * KOUT + threadIdx.x;
    for (int i = tid; i < KIN * KOUT; i += 256) Ws[i] = W[i];
    __syncthreads();
    const int n = threadIdx.x;
    const int ROWS = 256 / KOUT;
    for (int m = blockIdx.x * ROWS + threadIdx.y; m < M; m += gridDim.x * ROWS) {
        const float* a = A + (size_t)m * KIN;
        float acc = 0.0f;
#pragma unroll
        for (int k = 0; k < KIN; ++k) acc = fmaf(a[k], Ws[k * KOUT + n], acc);
        out[(size_t)m * KOUT + n] = acc;
    }
}

__global__ __launch_bounds__(256) void degree_kernel(const int* __restrict__ dst,
                                                     float* __restrict__ deg, int E) {
    for (int e = blockIdx.x * blockDim.x + threadIdx.x; e < E;
         e += gridDim.x * blockDim.x)
        atomicAdd(&deg[dst[e]], 1.0f);
}

// width-W scatter-add: thread i handles (edge i/W, feature i%W)
template<int W>
__global__ __launch_bounds__(256) void scatter_add_kernel(const float* __restrict__ msg,
                                                          const int* __restrict__ src,
                                                          const int* __restrict__ dst,
                                                          float* __restrict__ agg, int E) {
    const size_t total = (size_t)E * W;
    const size_t stride = (size_t)gridDim.x * blockDim.x;
    for (size_t i = (size_t)blockIdx.x * blockDim.x + threadIdx.x; i < total; i += stride) {
        const int e = (int)(i / W);
        const int k = (int)(i % W);
        atomicAdd(&agg[(size_t)dst[e] * W + k], msg[(size_t)src[e] * W + k]);
    }
}

// out[m][k] = agg[m][k]/max(deg[m],1) + self[m][k] + b[k]  (+ optional relu)
template<int W, bool RELU>
__global__ __launch_bounds__(256) void combine_kernel(const float* __restrict__ agg,
                                                      const float* __restrict__ selfb,
                                                      const float* __restrict__ deg,
                                                      const float* __restrict__ b,
                                                      float* __restrict__ out, int M) {
    const size_t total = (size_t)M * W;
    const size_t stride = (size_t)gridDim.x * blockDim.x;
    for (size_t i = (size_t)blockIdx.x * blockDim.x + threadIdx.x; i < total; i += stride) {
        const int m = (int)(i / W);
        const int k = (int)(i % W);
        float d = deg[m];
        d = d < 1.0f ? 1.0f : d;
        float v = agg[i] / d + selfb[i] + b[k];
        if (RELU) v = fmaxf(v, 0.0f);
        out[i] = v;
    }
}

// 8 lanes per edge; each lane loads a float4 slice of the 32-wide rows.
__global__ __launch_bounds__(256) void score_kernel(const float* __restrict__ h,
                                                    const int* __restrict__ src,
                                                    const int* __restrict__ dst,
                                                    const float* __restrict__ wrel,
                                                    float* __restrict__ out, int E) {
    const int lj = threadIdx.x & 7;             // lane within 8-lane group
    const size_t gid = (size_t)blockIdx.x * blockDim.x + threadIdx.x;
    const size_t grp = gid >> 3;
    const size_t ngrp = ((size_t)gridDim.x * blockDim.x) >> 3;
    const float4 w = *(const float4*)(wrel + lj * 4);
    for (size_t e = grp; e < (size_t)E; e += ngrp) {
        const int s = src[e], d = dst[e];
        const float4 hs = *(const float4*)(h + (size_t)s * 32 + lj * 4);
        const float4 hd = *(const float4*)(h + (size_t)d * 32 + lj * 4);
        float p = hs.x * w.x * hd.x + hs.y * w.y * hd.y +
                  hs.z * w.z * hd.z + hs.w * w.w * hd.w;
        p += __shfl_xor(p, 1, 64);
        p += __shfl_xor(p, 2, 64);
        p += __shfl_xor(p, 4, 64);
        if (lj == 0) out[e] = p;
    }
}

static inline int grid_for(size_t n, int cap) {
    size_t b = (n + 255) / 256;
    if (b > (size_t)cap) b = (size_t)cap;
    if (b < 1) b = 1;
    return (int)b;
}

extern "C" void kernel_launch(void* const* d_in, const int* in_sizes, int n_in,
                              void* d_out, int out_size, void* d_ws, size_t ws_size,
                              hipStream_t stream) {
    const float* feat_drug    = (const float*)d_in[0];
    const int*   dd_src       = (const int*)d_in[2];
    const int*   dd_dst       = (const int*)d_in[3];
    const int*   neg_src      = (const int*)d_in[8];
    const int*   neg_dst      = (const int*)d_in[9];
    const float* W1_dd        = (const float*)d_in[10];
    const float* W1_self_drug = (const float*)d_in[13];
    const float* b1           = (const float*)d_in[15];
    const float* W2_dd        = (const float*)d_in[16];
    const float* W2_self_drug = (const float*)d_in[19];
    const float* b2           = (const float*)d_in[21];
    const float* w_rel        = (const float*)d_in[22];

    const int N = in_sizes[0] / 128;   // 20000 drugs
    const int E = in_sizes[2];         // 1.5M dd edges
    const int EN = in_sizes[8];        // 1.5M neg edges

    // workspace layout (floats)
    float* ws    = (float*)d_ws;
    float* msg1  = ws;                              // N*64
    float* self1 = msg1  + (size_t)N * 64;          // N*64
    float* agg1  = self1 + (size_t)N * 64;          // N*64  (becomes h1)
    float* deg   = agg1  + (size_t)N * 64;          // N
    float* msg2  = deg   + N;                       // N*32
    float* self2 = msg2  + (size_t)N * 32;          // N*32
    float* agg2  = self2 + (size_t)N * 32;          // N*32  (becomes h2)

    float* pos = (float*)d_out;
    float* neg = pos + E;

    hipMemsetAsync(agg1, 0, (size_t)N * 64 * sizeof(float), stream);
    hipMemsetAsync(agg2, 0, (size_t)N * 32 * sizeof(float), stream);
    hipMemsetAsync(deg,  0, (size_t)N * sizeof(float), stream);

    // degree of dd_dst (shared across both layers)
    degree_kernel<<<grid_for(E, 2048), 256, 0, stream>>>(dd_dst, deg, E);

    // ---- layer 1 (drug path only) ----
    gemm_kernel<128, 64><<<(N + 3) / 4, dim3(64, 4), 0, stream>>>(feat_drug, W1_dd, msg1, N);
    gemm_kernel<128, 64><<<(N + 3) / 4, dim3(64, 4), 0, stream>>>(feat_drug, W1_self_drug, self1, N);
    scatter_add_kernel<64><<<grid_for((size_t)E * 64, 4096), 256, 0, stream>>>(msg1, dd_src, dd_dst, agg1, E);
    combine_kernel<64, true><<<grid_for((size_t)N * 64, 2048), 256, 0, stream>>>(agg1, self1, deg, b1, agg1, N);

    // ---- layer 2 (h1 lives in agg1) ----
    gemm_kernel<64, 32><<<(N + 7) / 8, dim3(32, 8), 0, stream>>>(agg1, W2_dd, msg2, N);
    gemm_kernel<64, 32><<<(N + 7) / 8, dim3(32, 8), 0, stream>>>(agg1, W2_self_drug, self2, N);
    scatter_add_kernel<32><<<grid_for((size_t)E * 32, 4096), 256, 0, stream>>>(msg2, dd_src, dd_dst, agg2, E);
    combine_kernel<32, false><<<grid_for((size_t)N * 32, 2048), 256, 0, stream>>>(agg2, self2, deg, b2, agg2, N);

    // ---- scorer (h2 lives in agg2) ----
    score_kernel<<<grid_for((size_t)E * 8, 4096), 256, 0, stream>>>(agg2, dd_src, dd_dst, w_rel, pos, E);
    score_kernel<<<grid_for((size_t)EN * 8, 4096), 256, 0, stream>>>(agg2, neg_src, neg_dst, w_rel, neg, EN);
}

// Round 2
// 396.313 us; speedup vs baseline: 1.7748x; 1.7748x over previous
//
#include <hip/hip_runtime.h>

// ---------------------------------------------------------------------------
// Drug-path-only GNN (gene path is dead code w.r.t. outputs).
// Round 2: replace fp32 atomic scatter-add (96M+48M atomics, 470us) with a
// CSR-by-dst build (cheap int atomics) + register-accumulating gather.
//   deg_i[n]   = #incoming dd edges               (int histogram)
//   offsets    = exclusive scan(deg_i)            (single-block scan)
//   csr_src[p] = src of edges bucketed by dst     (1 int atomic per edge)
//   msg1  = feat_drug @ W1_dd, self1 = feat_drug @ W1_self_drug
//   h1    = relu(gather-mean(msg1) + self1 + b1)  (fused epilogue, no atomics)
//   msg2  = h1 @ W2_dd, self2 = h1 @ W2_self_drug
//   h2    = gather-mean(msg2) + self2 + b2
//   pos/neg = per-edge weighted dot of h2 rows
// ---------------------------------------------------------------------------

template<int KIN, int KOUT>
__global__ __launch_bounds__(256) void gemm_kernel(const float* __restrict__ A,
                                                   const float* __restrict__ W,
                                                   float* __restrict__ out, int M) {
    __shared__ float Ws[KIN * KOUT];
    const int tid = threadIdx.y * KOUT + threadIdx.x;
    for (int i = tid; i < KIN * KOUT; i += 256) Ws[i] = W[i];
    __syncthreads();
    const int n = threadIdx.x;
    const int ROWS = 256 / KOUT;
    for (int m = blockIdx.x * ROWS + threadIdx.y; m < M; m += gridDim.x * ROWS) {
        const float* a = A + (size_t)m * KIN;
        float acc = 0.0f;
#pragma unroll
        for (int k = 0; k < KIN; ++k) acc = fmaf(a[k], Ws[k * KOUT + n], acc);
        out[(size_t)m * KOUT + n] = acc;
    }
}

__global__ __launch_bounds__(256) void degree_int_kernel(const int* __restrict__ dst,
                                                         int* __restrict__ deg, int E) {
    for (int e = blockIdx.x * blockDim.x + threadIdx.x; e < E;
         e += gridDim.x * blockDim.x)
        atomicAdd(&deg[dst[e]], 1);
}

// single-block exclusive scan over N<=20480 elements -> off[0..N], off[N]=total
__global__ __launch_bounds__(1024) void scan_kernel(const int* __restrict__ deg,
                                                    int* __restrict__ off, int N) {
    __shared__ int part[1024];
    const int t = threadIdx.x;
    const int per = (N + 1023) / 1024;
    const int beg = t * per;
    const int end = min(beg + per, N);
    int s = 0;
    for (int i = beg; i < end; ++i) s += deg[i];
    part[t] = s;
    __syncthreads();
    for (int d = 1; d < 1024; d <<= 1) {
        int v = (t >= d) ? part[t - d] : 0;
        __syncthreads();
        part[t] += v;
        __syncthreads();
    }
    int run = (t == 0) ? 0 : part[t - 1];
    for (int i = beg; i < end; ++i) { off[i] = run; run += deg[i]; }
    if (t == 1023) off[N] = part[1023];
}

__global__ __launch_bounds__(256) void fill_kernel(const int* __restrict__ src,
                                                   const int* __restrict__ dst,
                                                   const int* __restrict__ off,
                                                   int* __restrict__ cursor,
                                                   int* __restrict__ csr_src, int E) {
    for (int e = blockIdx.x * blockDim.x + threadIdx.x; e < E;
         e += gridDim.x * blockDim.x) {
        const int d = dst[e];
        const int p = off[d] + atomicAdd(&cursor[d], 1);
        csr_src[p] = src[e];
    }
}

// One W-lane group per dst node: register-accumulate incoming msg rows, then
// fused mean + self + bias (+relu).  256 threads = 256/W groups per block.
template<int W, bool RELU>
__global__ __launch_bounds__(256) void gather_combine_kernel(
        const float* __restrict__ msg, const int* __restrict__ csr_src,
        const int* __restrict__ off, const float* __restrict__ selfb,
        const float* __restrict__ b, float* __restrict__ out, int N) {
    const int GRP = 256 / W;
    const int g = threadIdx.x / W;
    const int lane = threadIdx.x % W;
    const float bk = b[lane];
    for (int n = blockIdx.x * GRP + g; n < N; n += gridDim.x * GRP) {
        const int beg = off[n], end = off[n + 1];
        float acc = 0.0f;
        int i = beg;
        for (; i + 4 <= end; i += 4) {
            const int s0 = csr_src[i], s1 = csr_src[i + 1];
            const int s2 = csr_src[i + 2], s3 = csr_src[i + 3];
            const float v0 = msg[(size_t)s0 * W + lane];
            const float v1 = msg[(size_t)s1 * W + lane];
            const float v2 = msg[(size_t)s2 * W + lane];
            const float v3 = msg[(size_t)s3 * W + lane];
            acc += (v0 + v1) + (v2 + v3);
        }
        for (; i < end; ++i) acc += msg[(size_t)csr_src[i] * W + lane];
        const float d = (end > beg) ? (float)(end - beg) : 1.0f;
        float v = acc / d + selfb[(size_t)n * W + lane] + bk;
        if (RELU) v = fmaxf(v, 0.0f);
        out[(size_t)n * W + lane] = v;
    }
}

// 8 lanes per edge; float4 slices of the 32-wide h rows.
__global__ __launch_bounds__(256) void score_kernel(const float* __restrict__ h,
                                                    const int* __restrict__ src,
                                                    const int* __restrict__ dst,
                                                    const float* __restrict__ wrel,
                                                    float* __restrict__ out, int E) {
    const int lj = threadIdx.x & 7;
    const size_t gid = (size_t)blockIdx.x * blockDim.x + threadIdx.x;
    const size_t grp = gid >> 3;
    const size_t ngrp = ((size_t)gridDim.x * blockDim.x) >> 3;
    const float4 w = *(const float4*)(wrel + lj * 4);
    for (size_t e = grp; e < (size_t)E; e += ngrp) {
        const int s = src[e], d = dst[e];
        const float4 hs = *(const float4*)(h + (size_t)s * 32 + lj * 4);
        const float4 hd = *(const float4*)(h + (size_t)d * 32 + lj * 4);
        float p = hs.x * w.x * hd.x + hs.y * w.y * hd.y +
                  hs.z * w.z * hd.z + hs.w * w.w * hd.w;
        p += __shfl_xor(p, 1, 64);
        p += __shfl_xor(p, 2, 64);
        p += __shfl_xor(p, 4, 64);
        if (lj == 0) out[e] = p;
    }
}

static inline int grid_for(size_t n, int cap) {
    size_t b = (n + 255) / 256;
    if (b > (size_t)cap) b = (size_t)cap;
    if (b < 1) b = 1;
    return (int)b;
}

extern "C" void kernel_launch(void* const* d_in, const int* in_sizes, int n_in,
                              void* d_out, int out_size, void* d_ws, size_t ws_size,
                              hipStream_t stream) {
    const float* feat_drug    = (const float*)d_in[0];
    const int*   dd_src       = (const int*)d_in[2];
    const int*   dd_dst       = (const int*)d_in[3];
    const int*   neg_src      = (const int*)d_in[8];
    const int*   neg_dst      = (const int*)d_in[9];
    const float* W1_dd        = (const float*)d_in[10];
    const float* W1_self_drug = (const float*)d_in[13];
    const float* b1           = (const float*)d_in[15];
    const float* W2_dd        = (const float*)d_in[16];
    const float* W2_self_drug = (const float*)d_in[19];
    const float* b2           = (const float*)d_in[21];
    const float* w_rel        = (const float*)d_in[22];

    const int N  = in_sizes[0] / 128;  // 20000 drugs
    const int E  = in_sizes[2];        // 1.5M dd edges
    const int EN = in_sizes[8];        // 1.5M neg edges

    // workspace layout (4-byte elements)
    char* ws = (char*)d_ws;
    int*   deg_i   = (int*)ws;                         ws += (size_t)N * 4;
    int*   cursor  = (int*)ws;                         ws += (size_t)N * 4;
    int*   off     = (int*)ws;                         ws += (size_t)(N + 1) * 4;
    int*   csr_src = (int*)ws;                         ws += (size_t)E * 4;
    float* msg1    = (float*)ws;                       ws += (size_t)N * 64 * 4;
    float* self1   = (float*)ws;                       ws += (size_t)N * 64 * 4;
    float* h1      = (float*)ws;                       ws += (size_t)N * 64 * 4;
    float* msg2    = (float*)ws;                       ws += (size_t)N * 32 * 4;
    float* self2   = (float*)ws;                       ws += (size_t)N * 32 * 4;
    float* h2      = (float*)ws;                       ws += (size_t)N * 32 * 4;

    float* pos = (float*)d_out;
    float* neg = pos + E;

    hipMemsetAsync(deg_i,  0, (size_t)N * sizeof(int), stream);
    hipMemsetAsync(cursor, 0, (size_t)N * sizeof(int), stream);

    // ---- CSR-by-dst build (shared by both layers) ----
    degree_int_kernel<<<grid_for(E, 2048), 256, 0, stream>>>(dd_dst, deg_i, E);
    scan_kernel<<<1, 1024, 0, stream>>>(deg_i, off, N);
    fill_kernel<<<grid_for(E, 2048), 256, 0, stream>>>(dd_src, dd_dst, off, cursor, csr_src, E);

    // ---- layer 1 ----
    gemm_kernel<128, 64><<<(N + 3) / 4, dim3(64, 4), 0, stream>>>(feat_drug, W1_dd, msg1, N);
    gemm_kernel<128, 64><<<(N + 3) / 4, dim3(64, 4), 0, stream>>>(feat_drug, W1_self_drug, self1, N);
    gather_combine_kernel<64, true><<<(N + 3) / 4, 256, 0, stream>>>(msg1, csr_src, off, self1, b1, h1, N);

    // ---- layer 2 ----
    gemm_kernel<64, 32><<<(N + 7) / 8, dim3(32, 8), 0, stream>>>(h1, W2_dd, msg2, N);
    gemm_kernel<64, 32><<<(N + 7) / 8, dim3(32, 8), 0, stream>>>(h1, W2_self_drug, self2, N);
    gather_combine_kernel<32, false><<<(N + 7) / 8, 256, 0, stream>>>(msg2, csr_src, off, self2, b2, h2, N);

    // ---- scorer ----
    score_kernel<<<grid_for((size_t)E * 8, 4096), 256, 0, stream>>>(h2, dd_src, dd_dst, w_rel, pos, E);
    score_kernel<<<grid_for((size_t)EN * 8, 4096), 256, 0, stream>>>(h2, neg_src, neg_dst, w_rel, neg, EN);
}